// Round 7
// baseline (230.739 us; speedup 1.0000x reference)
//
#include <hip/hip_runtime.h>

typedef __bf16 bf16;
typedef __bf16 bf16x2 __attribute__((ext_vector_type(2)));
typedef __bf16 bf16x4 __attribute__((ext_vector_type(4)));
typedef __bf16 bf16x8 __attribute__((ext_vector_type(8)));
typedef float f32x4 __attribute__((ext_vector_type(4)));

#define MFMA(a, b, c) __builtin_amdgcn_mfma_f32_16x16x32_bf16(a, b, c, 0, 0, 0)

#define GLD16(gptr, ldsptr)                                                        \
  __builtin_amdgcn_global_load_lds(                                                \
      (const __attribute__((address_space(1))) unsigned int*)(gptr),               \
      (__attribute__((address_space(3))) unsigned int*)(ldsptr), 16, 0, 0)

union I4B8 { int4 i; bf16x8 v; };
union HI { bf16x2 h; int i; };

// ---------------- fused cast (x, ctx) + weight transposes, one dispatch ----------------
// Wq is additionally scaled by 0.125*log2(e) so attention can use raw exp2.
__global__ __launch_bounds__(256) void prep_k(const float* __restrict__ x, bf16* __restrict__ xb,
                                              const float* __restrict__ ctx, bf16* __restrict__ ctxb,
                                              const float* __restrict__ Wq, bf16* __restrict__ WqT,
                                              const float* __restrict__ Wk, bf16* __restrict__ WkvT,
                                              const float* __restrict__ Wv,
                                              const float* __restrict__ Wo, bf16* __restrict__ WoT) {
  __shared__ float t[32][33];
  const int bid = blockIdx.x;
  if (bid < 5632) {  // casts
    const float* in; bf16* out; size_t i;
    if (bid < 4096) { in = x; out = xb; i = ((size_t)bid * 256 + threadIdx.x) * 8; }
    else { in = ctx; out = ctxb; i = ((size_t)(bid - 4096) * 256 + threadIdx.x) * 8; }
    const float4 a = *(const float4*)(in + i);
    const float4 b = *(const float4*)(in + i + 4);
    bf16x8 o;
    o[0] = (bf16)a.x; o[1] = (bf16)a.y; o[2] = (bf16)a.z; o[3] = (bf16)a.w;
    o[4] = (bf16)b.x; o[5] = (bf16)b.y; o[6] = (bf16)b.z; o[7] = (bf16)b.w;
    *(bf16x8*)(out + i) = o;
    return;
  }
  // transposes: out[C][R] = (bf16)(in[R][C] * sc)
  const int tt = bid - 5632;
  const int z = tt >> 10, rem = tt & 1023;
  const float* in; bf16* out; int R; float sc = 1.0f;
  if (z == 0)      { in = Wq; out = WqT;                R = 1024; sc = 0.18033688f; }
  else if (z == 1) { in = Wk; out = WkvT;               R = 768; }
  else if (z == 2) { in = Wv; out = WkvT + 1024 * 768;  R = 768; }
  else             { in = Wo; out = WoT;                R = 1024; }
  const int c0 = (rem & 31) * 32, r0 = (rem >> 5) * 32;
  if (r0 >= R) return;
  const int tx = threadIdx.x & 31, ty = threadIdx.x >> 5;
#pragma unroll
  for (int i = 0; i < 4; i++)
    t[ty + i * 8][tx] = in[(size_t)(r0 + ty + i * 8) * 1024 + c0 + tx];
  __syncthreads();
#pragma unroll
  for (int i = 0; i < 4; i++)
    out[(size_t)(c0 + ty + i * 8) * R + r0 + tx] = (bf16)(t[tx][ty + i * 8] * sc);
}

// ================= 256x256 phase-interleaved GEMM, HOISTED fragments =================
// (round-5 verified) 512 threads = 8 waves (2M x 4N), BM=BN=256, BK=64. LDS 128 KiB.
// Staging order A0,A1,B0,B1; vmcnt(2) at P0/P1 only; raw s_barrier per phase.
// Fragments read from LDS exactly once and held in registers across phases.
__device__ __forceinline__ void ld_af(bf16x8 (&af)[4][2], const bf16* Ls, int base,
                                      int wm, int c, int q, int swz) {
#pragma unroll
  for (int mi = 0; mi < 4; mi++) {
    const int rr = wm * 64 + mi * 16 + c;
#pragma unroll
    for (int kk = 0; kk < 2; kk++)
      af[mi][kk] = *(const bf16x8*)&Ls[base + rr * 64 + ((kk * 32 + q * 8) ^ swz)];
  }
}
__device__ __forceinline__ void ld_bb(bf16x8 (&bb)[2][2], const bf16* Ls, int base,
                                      int wn, int c, int q, int swz) {
#pragma unroll
  for (int ni = 0; ni < 2; ni++) {
    const int rn = wn * 32 + ni * 16 + c;
#pragma unroll
    for (int kk = 0; kk < 2; kk++)
      bb[ni][kk] = *(const bf16x8*)&Ls[base + rn * 64 + ((kk * 32 + q * 8) ^ swz)];
  }
}
template <int MODE>
__device__ __forceinline__ void mma16(f32x4 (&pacc)[4][2], const bf16x8 (&af)[4][2],
                                      const bf16x8 (&bb)[2][2]) {
  __builtin_amdgcn_s_setprio(1);
#pragma unroll
  for (int mi = 0; mi < 4; mi++)
#pragma unroll
    for (int ni = 0; ni < 2; ni++)
#pragma unroll
      for (int kk = 0; kk < 2; kk++) {
        if constexpr (MODE == 2)
          pacc[mi][ni] = MFMA(af[mi][kk], bb[ni][kk], pacc[mi][ni]);   // D[m][n]
        else
          pacc[mi][ni] = MFMA(bb[ni][kk], af[mi][kk], pacc[mi][ni]);   // D[n][m]
      }
  __builtin_amdgcn_s_setprio(0);
}

template <int MODE>
__device__ __forceinline__ void gemm256(const bf16* __restrict__ A,
                                        const bf16* __restrict__ Bt,
                                        int K, int m0, int n0,
                                        void* __restrict__ C0,
                                        const float* __restrict__ bias,
                                        bf16* Ls) {
  const int tid = threadIdx.x;
  const int lane = tid & 63, w = tid >> 6;   // 8 waves
  const int wm = w >> 2, wn = w & 3;         // 2M x 4N -> per-wave 128x64
  const int q = lane >> 4, c = lane & 15;
  const int swz = (c & 7) * 8;

  const int rl = tid >> 3, seg = tid & 7;
  const bf16* Ag = A + (size_t)(m0 + rl) * K + ((seg ^ (rl & 7)) * 8);
  const bf16* Bg = Bt + (size_t)(n0 + rl) * K + ((seg ^ (rl & 7)) * 8);
  const size_t K64 = (size_t)K * 64, K128 = (size_t)K * 128;
  const int ws = w * 512;

  f32x4 acc[2][2][4][2] = {};  // [h][g][mi][ni]

  // prologue: stage tile0 halves in order A0, A1, B0, B1 into buf0
  GLD16(Ag,              &Ls[0 + ws]);
  GLD16(Ag + K64,        &Ls[4096 + ws]);
  GLD16(Ag + K128,       &Ls[8192 + ws]);
  GLD16(Ag + K128 + K64, &Ls[12288 + ws]);
  GLD16(Bg,              &Ls[32768 + ws]);
  GLD16(Bg + K64,        &Ls[32768 + 4096 + ws]);
  GLD16(Bg + K128,       &Ls[32768 + 8192 + ws]);
  GLD16(Bg + K128 + K64, &Ls[32768 + 12288 + ws]);

  int cur = 0;
  for (int k0 = 0; k0 < K; k0 += 64) {
    const int nxt = cur ^ 1;
    // last tile re-stages itself (never read) to keep vmcnt arithmetic uniform
    const size_t kn = (size_t)((k0 + 64 < K) ? k0 + 64 : k0);
    const int Ab = cur * 16384, Bb = 32768 + cur * 16384;
    const int An = nxt * 16384, Bn = 32768 + nxt * 16384;

    bf16x8 af[4][2], b0[2][2], b1[2][2];

    // ---- P0: (h0,g0); needs A0,A1,B0 of cur -> vmcnt(2); stage A0(next) ----
    asm volatile("s_waitcnt vmcnt(2)" ::: "memory");
    asm volatile("s_barrier" ::: "memory");
    GLD16(Ag + kn,       &Ls[An + ws]);
    GLD16(Ag + kn + K64, &Ls[An + 4096 + ws]);
    ld_af(af, Ls, Ab, wm, c, q, swz);
    ld_bb(b0, Ls, Bb, wn, c, q, swz);
    mma16<MODE>(acc[0][0], af, b0);

    // ---- P1: (h0,g1); needs B1 of cur -> vmcnt(2); stage A1(next) ----
    asm volatile("s_waitcnt vmcnt(2)" ::: "memory");
    asm volatile("s_barrier" ::: "memory");
    GLD16(Ag + kn + K128,       &Ls[An + 8192 + ws]);
    GLD16(Ag + kn + K128 + K64, &Ls[An + 12288 + ws]);
    ld_bb(b1, Ls, Bb + 8192, wn, c, q, swz);
    mma16<MODE>(acc[0][1], af, b1);

    // ---- P2: (h1,g0); stage B0(next) ----
    asm volatile("s_barrier" ::: "memory");
    GLD16(Bg + kn,       &Ls[Bn + ws]);
    GLD16(Bg + kn + K64, &Ls[Bn + 4096 + ws]);
    ld_af(af, Ls, Ab + 8192, wm, c, q, swz);
    mma16<MODE>(acc[1][0], af, b0);

    // ---- P3: (h1,g1); no ds_read; stage B1(next) ----
    asm volatile("s_barrier" ::: "memory");
    GLD16(Bg + kn + K128,       &Ls[Bn + 8192 + ws]);
    GLD16(Bg + kn + K128 + K64, &Ls[Bn + 12288 + ws]);
    mma16<MODE>(acc[1][1], af, b1);

    cur = nxt;
  }
  asm volatile("s_waitcnt vmcnt(0)" ::: "memory");  // clean exit

  if constexpr (MODE == 0 || MODE == 1) {
#pragma unroll
    for (int h = 0; h < 2; h++)
#pragma unroll
      for (int g = 0; g < 2; g++)
#pragma unroll
        for (int ni = 0; ni < 2; ni++) {
          const int col = n0 + g * 128 + wn * 32 + ni * 16 + q * 4;
          float4 bv4 = {};
          if constexpr (MODE == 1) bv4 = *(const float4*)&bias[col];
#pragma unroll
          for (int mi = 0; mi < 4; mi++) {
            const int row = m0 + h * 128 + wm * 64 + mi * 16 + c;
            if constexpr (MODE == 0) {
              bf16x4 vv;
#pragma unroll
              for (int r2 = 0; r2 < 4; r2++) vv[r2] = (bf16)acc[h][g][mi][ni][r2];
              *(bf16x4*)&((bf16*)C0)[(size_t)row * 1024 + col] = vv;
            } else {
              f32x4 vv;
              vv[0] = acc[h][g][mi][ni][0] + bv4.x; vv[1] = acc[h][g][mi][ni][1] + bv4.y;
              vv[2] = acc[h][g][mi][ni][2] + bv4.z; vv[3] = acc[h][g][mi][ni][3] + bv4.w;
              *(f32x4*)&((float*)C0)[(size_t)row * 1024 + col] = vv;
            }
          }
        }
  } else {
    // normal: lane (q,c) holds rows rbase+q*4..+3 (keys), col fixed; sigma scatter.
#pragma unroll
    for (int h = 0; h < 2; h++)
#pragma unroll
      for (int g = 0; g < 2; g++)
#pragma unroll
        for (int ni = 0; ni < 2; ni++) {
          const int col = n0 + g * 128 + wn * 32 + ni * 16 + c;
#pragma unroll
          for (int mi = 0; mi < 4; mi++) {
            const int rbase = m0 + h * 128 + wm * 64 + mi * 16 + q * 4;
            const int b = rbase >> 10, key = rbase & 1023;
            bf16* VT = (bf16*)C0;
            const int hh = col >> 6, d = col & 63;
            const int kl = key & 63;
            const int pkey = (key & ~63) | (kl & 32) | ((kl & 12) << 1) | ((kl & 16) >> 2);
            bf16x4 vv;
#pragma unroll
            for (int r2 = 0; r2 < 4; r2++) vv[r2] = (bf16)acc[h][g][mi][ni][r2];
            *(bf16x4*)&VT[((size_t)(b * 16 + hh) * 64 + d) * 1024 + pkey] = vv;
          }
        }
  }
}

// ---------------- fused Q+K+V projections, 256 blocks x 512 threads ----------------
__global__ __launch_bounds__(512) void proj_k(const bf16* __restrict__ xb,
                                              const bf16* __restrict__ ctxb,
                                              const bf16* __restrict__ WqT,
                                              const bf16* __restrict__ WkvT,
                                              bf16* __restrict__ Q,
                                              bf16* __restrict__ Kp,
                                              bf16* __restrict__ VT) {
  extern __shared__ __align__(16) bf16 Ls[];
  const int bid = blockIdx.x;
  if (bid < 128) {        // Q: M=8192 (32 rt), N=1024 (4 ct), K=1024
    const int x = bid & 7, i = bid >> 3;         // i 0..15
    const int rt = x * 4 + (i >> 2), ct = i & 3;
    gemm256<0>(xb, WqT, 1024, rt * 256, ct * 256, Q, nullptr, Ls);
  } else if (bid < 192) { // K: M=4096 (16 rt), N=1024, K=768
    const int t = bid - 128, x = t & 7, i = t >> 3;  // i 0..7
    const int rt = x * 2 + (i >> 2), ct = i & 3;
    gemm256<0>(ctxb, WkvT, 768, rt * 256, ct * 256, Kp, nullptr, Ls);
  } else {                // V: M=4096, N=1024, K=768 -> sigma V^T
    const int t = bid - 192, x = t & 7, i = t >> 3;
    const int rt = x * 2 + (i >> 2), ct = i & 3;
    gemm256<2>(ctxb, WkvT + (size_t)1024 * 768, 768, rt * 256, ct * 256, VT, nullptr, Ls);
  }
}

// ---------------- output projection (round-3/4 known-good 128x128 body) ----------------
__device__ __forceinline__ void gemm_body_out(const bf16* __restrict__ A,
                                              const bf16* __restrict__ Bt,
                                              int K, int m0, int n0,
                                              float* __restrict__ C0,
                                              const float* __restrict__ bias,
                                              bf16* As, bf16* Bs) {
  const int tid = threadIdx.x;
  const int lane = tid & 63, wave = tid >> 6;
  const int wm = wave >> 1, wn = wave & 1;
  const int q = lane >> 4, c = lane & 15;

  f32x4 acc[4][4] = {};
  const int r = tid >> 3;
  const int col8 = ((tid & 7) * 8) ^ ((r & 7) * 8);
  const bf16* Ag = A + (size_t)(m0 + r) * K + col8;
  const bf16* Bg = Bt + (size_t)(n0 + r) * K + col8;
  const size_t K32 = (size_t)K * 32;
  bf16* AsW = As + wave * 512;
  bf16* BsW = Bs + wave * 512;
  const int swz = (c & 7) * 8;

  for (int k0 = 0; k0 < K; k0 += 64) {
    __syncthreads();
    GLD16(Ag + k0,            AsW);
    GLD16(Ag + k0 + K32,      AsW + 2048);
    GLD16(Ag + k0 + 2 * K32,  AsW + 4096);
    GLD16(Ag + k0 + 3 * K32,  AsW + 6144);
    GLD16(Bg + k0,            BsW);
    GLD16(Bg + k0 + K32,      BsW + 2048);
    GLD16(Bg + k0 + 2 * K32,  BsW + 4096);
    GLD16(Bg + k0 + 3 * K32,  BsW + 6144);
    __syncthreads();
#pragma unroll
    for (int kk = 0; kk < 2; kk++) {
      const int cx = (kk * 32 + q * 8) ^ swz;
      bf16x8 af[4], bfr[4];
#pragma unroll
      for (int mi = 0; mi < 4; mi++)
        af[mi] = *(const bf16x8*)&As[(wm * 64 + mi * 16 + c) * 64 + cx];
#pragma unroll
      for (int ni = 0; ni < 4; ni++)
        bfr[ni] = *(const bf16x8*)&Bs[(wn * 64 + ni * 16 + c) * 64 + cx];
      __builtin_amdgcn_s_setprio(1);
#pragma unroll
      for (int mi = 0; mi < 4; mi++)
#pragma unroll
        for (int ni = 0; ni < 4; ni++)
          acc[mi][ni] = MFMA(bfr[ni], af[mi], acc[mi][ni]);   // D[n][m]
      __builtin_amdgcn_s_setprio(0);
    }
  }

#pragma unroll
  for (int ni = 0; ni < 4; ni++) {
    const int col = n0 + wn * 64 + ni * 16 + q * 4;
    float4 bv4 = *(const float4*)&bias[col];
#pragma unroll
    for (int mi = 0; mi < 4; mi++) {
      const int row = m0 + wm * 64 + mi * 16 + c;
      f32x4 vv;
      vv[0] = acc[mi][ni][0] + bv4.x; vv[1] = acc[mi][ni][1] + bv4.y;
      vv[2] = acc[mi][ni][2] + bv4.z; vv[3] = acc[mi][ni][3] + bv4.w;
      *(f32x4*)&C0[(size_t)row * 1024 + col] = vv;
    }
  }
}

__global__ __launch_bounds__(256) void out_k(const bf16* __restrict__ O,
                                             const bf16* __restrict__ WoT,
                                             float* __restrict__ out,
                                             const float* __restrict__ bo) {
  __shared__ __align__(16) bf16 As[8192];
  __shared__ __align__(16) bf16 Bs[8192];
  const int bid = blockIdx.x;
  const int s = (bid & 7) * 64 + (bid >> 3);   // XCD chunk-swizzle
  gemm_body_out(O, WoT, 1024, (s >> 3) * 128, (s & 7) * 128, out, bo, As, Bs);
}

// ---------------- flash attention: pk-PIPELINED, 3-buffer LDS, 1 barrier/tile ----------------
// 512 blocks, 4 waves, 64 q-rows/wave. The round-6 serial chain QK->exp->PV is
// broken by carrying the PACKED P (pk, 32 VGPR) across the barrier:
//   iter t: [issue loads t+1] -> QK(t) MFMA -> PV(t-1) MFMA (uses pk from t-1)
//           -> exp(st)->pk(t) -> [write t+1 -> buf (t+1)%3] -> barrier
// MFMA pipe gets 72 back-to-back issues; the in-order wave then issues exp VALU
// while the MFMA latencies drain -> single-wave MFMA/VALU overlap. exp leaves
// the MFMA->MFMA critical path. 3-buffer rotation (48KB LDS, 2 blocks/CU) keeps
// one barrier/tile with clean WAR: the buffer written at iter t ((t+1)%3) was
// last read at iter t-1 (PV(t-2)), before iter t-1's barrier. Global loads'
// first use is the ds_write AFTER exp, so vmcnt waits land after ~full compute.
// Swizzled [64][64] layout (round-6 verified, conflict-free both sides).
__global__ __launch_bounds__(256, 2) void attn_k(const bf16* __restrict__ Qg,
                                                 const bf16* __restrict__ Kg,
                                                 const bf16* __restrict__ VTg,
                                                 bf16* __restrict__ Og) {
  __shared__ __align__(16) bf16 Ks[3][64][64];
  __shared__ __align__(16) bf16 Vt[3][64][64];
  const int tid = threadIdx.x;
  const int lane = tid & 63, w = tid >> 6;
  const int q = lane >> 4, c = lane & 15;
  const int bid = blockIdx.x;                  // 512 flat
  const int pair = (bid & 7) * 8 + (bid >> 6); // 0..63 ; 8 pairs per XCD
  const int head = pair & 15, b = pair >> 4;
  const int q0 = ((bid >> 3) & 7) * 256;

  bf16x8 aQ[4][2];
#pragma unroll
  for (int mj = 0; mj < 4; mj++)
#pragma unroll
    for (int ks = 0; ks < 2; ks++)
      aQ[mj][ks] = *(const bf16x8*)(Qg + (size_t)(b * 2048 + q0 + w * 64 + mj * 16 + c) * 1024 +
                                    head * 64 + ks * 32 + q * 8);

  f32x4 o[4][4] = {};
  f32x4 ol[4] = {};  // l via ones-MFMA: lane (q,c) reg r = l[qrow mi*16+q*4+r]
  bf16x8 vone;
#pragma unroll
  for (int i = 0; i < 8; i++) vone[i] = (bf16)1.0f;

  const int srow = tid >> 2, sc = tid & 3;
  const int ws0 = ((2 * sc) ^ (srow & 7)) * 8;      // swizzled write slots
  const int ws1 = ((2 * sc + 1) ^ (srow & 7)) * 8;
  const int rsw = c & 7;                            // read-side slot XOR
  const bf16* Kbase = Kg + (size_t)(b * 1024 + srow) * 1024 + head * 64 + sc * 16;
  const bf16* Vbase = VTg + ((size_t)(b * 16 + head) * 64 + srow) * 1024 + sc * 16;

  // prologue: tile0 -> buf0; issue tile1 loads; barrier; QK(0); exp->pk; write buf1; barrier
  bf16x8 rk0 = *(const bf16x8*)(Kbase);
  bf16x8 rk1 = *(const bf16x8*)(Kbase + 8);
  bf16x8 rv0 = *(const bf16x8*)(Vbase);
  bf16x8 rv1 = *(const bf16x8*)(Vbase + 8);
  *(bf16x8*)&Ks[0][srow][ws0] = rk0;
  *(bf16x8*)&Ks[0][srow][ws1] = rk1;
  *(bf16x8*)&Vt[0][srow][ws0] = rv0;
  *(bf16x8*)&Vt[0][srow][ws1] = rv1;
  rk0 = *(const bf16x8*)(Kbase + 65536);
  rk1 = *(const bf16x8*)(Kbase + 65536 + 8);
  rv0 = *(const bf16x8*)(Vbase + 64);
  rv1 = *(const bf16x8*)(Vbase + 64 + 8);
  __syncthreads();

  int pk[4][4][2];
  {
    f32x4 st[4][4] = {};
#pragma unroll
    for (int ks = 0; ks < 2; ks++) {
      bf16x8 ak[4];
#pragma unroll
      for (int ni = 0; ni < 4; ni++)
        ak[ni] = *(const bf16x8*)&Ks[0][ni * 16 + c][((ks * 4 + q) ^ rsw) * 8];
      __builtin_amdgcn_s_setprio(1);
#pragma unroll
      for (int mj = 0; mj < 4; mj++)
#pragma unroll
        for (int ni = 0; ni < 4; ni++)
          st[mj][ni] = MFMA(ak[ni], aQ[mj][ks], st[mj][ni]);
      __builtin_amdgcn_s_setprio(0);
    }
#pragma unroll
    for (int mj = 0; mj < 4; mj++)
#pragma unroll
      for (int ni = 0; ni < 4; ni++) {
        float p0 = __builtin_amdgcn_exp2f(st[mj][ni][0]);
        float p1 = __builtin_amdgcn_exp2f(st[mj][ni][1]);
        float p2 = __builtin_amdgcn_exp2f(st[mj][ni][2]);
        float p3 = __builtin_amdgcn_exp2f(st[mj][ni][3]);
        HI h0, h1;
        h0.h[0] = (bf16)p0; h0.h[1] = (bf16)p1;
        h1.h[0] = (bf16)p2; h1.h[1] = (bf16)p3;
        pk[mj][ni][0] = h0.i;
        pk[mj][ni][1] = h1.i;
      }
  }
  *(bf16x8*)&Ks[1][srow][ws0] = rk0;
  *(bf16x8*)&Ks[1][srow][ws1] = rk1;
  *(bf16x8*)&Vt[1][srow][ws0] = rv0;
  *(bf16x8*)&Vt[1][srow][ws1] = rv1;
  __syncthreads();

#pragma unroll 1
  for (int kt = 1; kt < 16; kt++) {
    const int cur = kt % 3;            // holds K of tile kt
    const int prv = (kt + 2) % 3;      // holds V of tile kt-1
    const int nb  = (kt + 1) % 3;
    if (kt < 15) {  // issue tile kt+1 loads; first USE is the ds_write after exp
      const size_t ko = (size_t)(kt + 1) * 65536;
      const int vo = (kt + 1) * 64;
      rk0 = *(const bf16x8*)(Kbase + ko);
      rk1 = *(const bf16x8*)(Kbase + ko + 8);
      rv0 = *(const bf16x8*)(Vbase + vo);
      rv1 = *(const bf16x8*)(Vbase + vo + 8);
    }

    // QK(kt): S^T = K @ Q^T -> st (consumed by exp below, NOT by PV this iter)
    f32x4 st[4][4] = {};
#pragma unroll
    for (int ks = 0; ks < 2; ks++) {
      bf16x8 ak[4];
#pragma unroll
      for (int ni = 0; ni < 4; ni++)
        ak[ni] = *(const bf16x8*)&Ks[cur][ni * 16 + c][((ks * 4 + q) ^ rsw) * 8];
      __builtin_amdgcn_s_setprio(1);
#pragma unroll
      for (int mj = 0; mj < 4; mj++)
#pragma unroll
        for (int ni = 0; ni < 4; ni++)
          st[mj][ni] = MFMA(ak[ni], aQ[mj][ks], st[mj][ni]);
      __builtin_amdgcn_s_setprio(0);
    }

    // PV(kt-1): uses pk carried from last iter; V from buf[prv]
#pragma unroll
    for (int ks2 = 0; ks2 < 2; ks2++) {
      bf16x8 bv[4];
#pragma unroll
      for (int ni = 0; ni < 4; ni++)
        bv[ni] = *(const bf16x8*)&Vt[prv][ni * 16 + c][((ks2 * 4 + q) ^ rsw) * 8];
#pragma unroll
      for (int mi = 0; mi < 4; mi++) {
        I4B8 pa;
        pa.i.x = pk[mi][2 * ks2][0];
        pa.i.y = pk[mi][2 * ks2][1];
        pa.i.z = pk[mi][2 * ks2 + 1][0];
        pa.i.w = pk[mi][2 * ks2 + 1][1];
        __builtin_amdgcn_s_setprio(1);
#pragma unroll
        for (int ni = 0; ni < 4; ni++)
          o[mi][ni] = MFMA(pa.v, bv[ni], o[mi][ni]);
        ol[mi] = MFMA(pa.v, vone, ol[mi]);
        __builtin_amdgcn_s_setprio(0);
      }
    }

    // exp(st) -> pk (tile kt); VALU executes while the MFMA pipe drains
#pragma unroll
    for (int mj = 0; mj < 4; mj++)
#pragma unroll
      for (int ni = 0; ni < 4; ni++) {
        float p0 = __builtin_amdgcn_exp2f(st[mj][ni][0]);
        float p1 = __builtin_amdgcn_exp2f(st[mj][ni][1]);
        float p2 = __builtin_amdgcn_exp2f(st[mj][ni][2]);
        float p3 = __builtin_amdgcn_exp2f(st[mj][ni][3]);
        HI h0, h1;
        h0.h[0] = (bf16)p0; h0.h[1] = (bf16)p1;
        h1.h[0] = (bf16)p2; h1.h[1] = (bf16)p3;
        pk[mj][ni][0] = h0.i;
        pk[mj][ni][1] = h1.i;
      }

    if (kt < 15) {  // write tile kt+1 -> buf[nb]; prior readers done >=1 barrier ago
      *(bf16x8*)&Ks[nb][srow][ws0] = rk0;
      *(bf16x8*)&Ks[nb][srow][ws1] = rk1;
      *(bf16x8*)&Vt[nb][srow][ws0] = rv0;
      *(bf16x8*)&Vt[nb][srow][ws1] = rv1;
    }
    __syncthreads();
  }

  // epilogue: PV(15) — tile 15 lives in buffer 15%3 == 0
#pragma unroll
  for (int ks2 = 0; ks2 < 2; ks2++) {
    bf16x8 bv[4];
#pragma unroll
    for (int ni = 0; ni < 4; ni++)
      bv[ni] = *(const bf16x8*)&Vt[0][ni * 16 + c][((ks2 * 4 + q) ^ rsw) * 8];
#pragma unroll
    for (int mi = 0; mi < 4; mi++) {
      I4B8 pa;
      pa.i.x = pk[mi][2 * ks2][0];
      pa.i.y = pk[mi][2 * ks2][1];
      pa.i.z = pk[mi][2 * ks2 + 1][0];
      pa.i.w = pk[mi][2 * ks2 + 1][1];
#pragma unroll
      for (int ni = 0; ni < 4; ni++)
        o[mi][ni] = MFMA(pa.v, bv[ni], o[mi][ni]);
      ol[mi] = MFMA(pa.v, vone, ol[mi]);
    }
  }

  // normalize + store: ol[mi][r] is l for qrow mi*16+q*4+r (every c holds a copy)
#pragma unroll
  for (int mi = 0; mi < 4; mi++) {
    float inv[4];
#pragma unroll
    for (int r = 0; r < 4; r++) inv[r] = 1.0f / ol[mi][r];
#pragma unroll
    for (int ni = 0; ni < 4; ni++)
#pragma unroll
      for (int r = 0; r < 4; r++) {
        const int qrow = q0 + w * 64 + mi * 16 + q * 4 + r;
        const int col = head * 64 + ni * 16 + c;
        Og[(size_t)(b * 2048 + qrow) * 1024 + col] = (bf16)(o[mi][ni][r] * inv[r]);
      }
  }
}

extern "C" void kernel_launch(void* const* d_in, const int* in_sizes, int n_in,
                              void* d_out, int out_size, void* d_ws, size_t ws_size,
                              hipStream_t stream) {
  (void)in_sizes; (void)n_in; (void)out_size; (void)ws_size;
  const float* x   = (const float*)d_in[0];
  const float* ctx = (const float*)d_in[1];
  const float* Wq  = (const float*)d_in[2];
  const float* Wk  = (const float*)d_in[3];
  const float* Wv  = (const float*)d_in[4];
  const float* Wo  = (const float*)d_in[5];
  const float* bo  = (const float*)d_in[6];
  float* out = (float*)d_out;

  char* ws = (char*)d_ws;
  const size_t MB = 1u << 20;
  bf16* WqT  = (bf16*)(ws);                 // 2 MiB   [1024][1024] (x 0.18033688)
  bf16* WkvT = (bf16*)(ws + 2 * MB);        // 3 MiB   [2048][768]
  bf16* WoT  = (bf16*)(ws + 5 * MB);        // 2 MiB
  bf16* ctxb = (bf16*)(ws + 7 * MB);        // 6 MiB   [4096][768]
  bf16* xb   = (bf16*)(ws + 13 * MB);       // 16 MiB  [8192][1024]; reused as O after Q-proj
  bf16* Q    = (bf16*)(ws + 29 * MB);       // 16 MiB
  bf16* Kp   = (bf16*)(ws + 45 * MB);       // 8 MiB
  bf16* VT   = (bf16*)(ws + 53 * MB);       // 8 MiB   [4][16][64][1024] sigma-permuted keys
  bf16* O    = xb;

  prep_k<<<5632 + 4096, 256, 0, stream>>>(x, xb, ctx, ctxb, Wq, WqT, Wk, WkvT, Wv, Wo, WoT);

  proj_k<<<256, 512, 131072, stream>>>(xb, ctxb, WqT, WkvT, Q, Kp, VT);

  attn_k<<<512, 256, 0, stream>>>(Q, Kp, VT, O);

  out_k<<<512, 256, 0, stream>>>(O, WoT, out, bo);
}

// Round 9
// 201.153 us; speedup vs baseline: 1.1471x; 1.1471x over previous
//
#include <hip/hip_runtime.h>

typedef __bf16 bf16;
typedef __bf16 bf16x2 __attribute__((ext_vector_type(2)));
typedef __bf16 bf16x4 __attribute__((ext_vector_type(4)));
typedef __bf16 bf16x8 __attribute__((ext_vector_type(8)));
typedef float f32x4 __attribute__((ext_vector_type(4)));

#define MFMA(a, b, c) __builtin_amdgcn_mfma_f32_16x16x32_bf16(a, b, c, 0, 0, 0)

#define GLD16(gptr, ldsptr)                                                        \
  __builtin_amdgcn_global_load_lds(                                                \
      (const __attribute__((address_space(1))) unsigned int*)(gptr),               \
      (__attribute__((address_space(3))) unsigned int*)(ldsptr), 16, 0, 0)

union I4B8 { int4 i; bf16x8 v; };
union HI { bf16x2 h; int i; };

// ---------------- fused cast (x, ctx) + weight transposes, one dispatch ----------------
// Wq is additionally scaled by 0.125*log2(e) so attention can use raw exp2.
__global__ __launch_bounds__(256) void prep_k(const float* __restrict__ x, bf16* __restrict__ xb,
                                              const float* __restrict__ ctx, bf16* __restrict__ ctxb,
                                              const float* __restrict__ Wq, bf16* __restrict__ WqT,
                                              const float* __restrict__ Wk, bf16* __restrict__ WkvT,
                                              const float* __restrict__ Wv,
                                              const float* __restrict__ Wo, bf16* __restrict__ WoT) {
  __shared__ float t[32][33];
  const int bid = blockIdx.x;
  if (bid < 5632) {  // casts
    const float* in; bf16* out; size_t i;
    if (bid < 4096) { in = x; out = xb; i = ((size_t)bid * 256 + threadIdx.x) * 8; }
    else { in = ctx; out = ctxb; i = ((size_t)(bid - 4096) * 256 + threadIdx.x) * 8; }
    const float4 a = *(const float4*)(in + i);
    const float4 b = *(const float4*)(in + i + 4);
    bf16x8 o;
    o[0] = (bf16)a.x; o[1] = (bf16)a.y; o[2] = (bf16)a.z; o[3] = (bf16)a.w;
    o[4] = (bf16)b.x; o[5] = (bf16)b.y; o[6] = (bf16)b.z; o[7] = (bf16)b.w;
    *(bf16x8*)(out + i) = o;
    return;
  }
  // transposes: out[C][R] = (bf16)(in[R][C] * sc)
  const int tt = bid - 5632;
  const int z = tt >> 10, rem = tt & 1023;
  const float* in; bf16* out; int R; float sc = 1.0f;
  if (z == 0)      { in = Wq; out = WqT;                R = 1024; sc = 0.18033688f; }
  else if (z == 1) { in = Wk; out = WkvT;               R = 768; }
  else if (z == 2) { in = Wv; out = WkvT + 1024 * 768;  R = 768; }
  else             { in = Wo; out = WoT;                R = 1024; }
  const int c0 = (rem & 31) * 32, r0 = (rem >> 5) * 32;
  if (r0 >= R) return;
  const int tx = threadIdx.x & 31, ty = threadIdx.x >> 5;
#pragma unroll
  for (int i = 0; i < 4; i++)
    t[ty + i * 8][tx] = in[(size_t)(r0 + ty + i * 8) * 1024 + c0 + tx];
  __syncthreads();
#pragma unroll
  for (int i = 0; i < 4; i++)
    out[(size_t)(c0 + ty + i * 8) * R + r0 + tx] = (bf16)(t[tx][ty + i * 8] * sc);
}

// ================= 256x256 GEMM, m201-faithful dual-barrier phases =================
// 512 threads = 8 waves (2M x 4N), BM=BN=256, BK=64, LDS 128 KiB, dbuf.
// Per phase: {GLD16 stage ; ds_read frags ; [counted vmcnt] ; s_barrier ;
//   lgkmcnt(0) ; sched_barrier(0) ; setprio(1) 16xMFMA setprio(0) ; s_barrier}.
// ds_reads are issued BEFORE the mid-barrier (latency overlaps the barrier wait);
// their staging was drained by a PREVIOUS phase's counted vmcnt + barrier:
//   P0 reads A0,A1,B0,B1(t) <- P3(t-1)'s vmcnt(2) (drains 6, leaves B2,B3) ;
//   P1 reads B2,B3(t)       <- P0's vmcnt(2) ;
//   P2 reads A2,A3(t)       <- P3(t-1)'s vmcnt(2) ;
//   iter 0 has no previous phase -> PROLOGUE DRAIN vmcnt(0)+s_barrier is REQUIRED
//   (round-8 NaN: missing drain = first-tile ds_reads sampled uninitialized LDS;
//   a ds_read samples LDS at issue, a later vmcnt cannot retroactively fix it).
// In-flight: 2 -> (P0 +2, wait) 2 -> 4 -> 6 -> (P3 +2, wait) 2; never 0 in-loop.
// WAR on buf nxt: first overwrite lands >=7 barriers after its last reader.
// Fragments hoisted (each LDS byte read once): P0 12 reads, P1 4, P2 8, P3 0.
__device__ __forceinline__ void ld_af(bf16x8 (&af)[4][2], const bf16* Ls, int base,
                                      int wm, int c, int q, int swz) {
#pragma unroll
  for (int mi = 0; mi < 4; mi++) {
    const int rr = wm * 64 + mi * 16 + c;
#pragma unroll
    for (int kk = 0; kk < 2; kk++)
      af[mi][kk] = *(const bf16x8*)&Ls[base + rr * 64 + ((kk * 32 + q * 8) ^ swz)];
  }
}
__device__ __forceinline__ void ld_bb(bf16x8 (&bb)[2][2], const bf16* Ls, int base,
                                      int wn, int c, int q, int swz) {
#pragma unroll
  for (int ni = 0; ni < 2; ni++) {
    const int rn = wn * 32 + ni * 16 + c;
#pragma unroll
    for (int kk = 0; kk < 2; kk++)
      bb[ni][kk] = *(const bf16x8*)&Ls[base + rn * 64 + ((kk * 32 + q * 8) ^ swz)];
  }
}
template <int MODE>
__device__ __forceinline__ void mma16(f32x4 (&pacc)[4][2], const bf16x8 (&af)[4][2],
                                      const bf16x8 (&bb)[2][2]) {
  __builtin_amdgcn_s_setprio(1);
#pragma unroll
  for (int mi = 0; mi < 4; mi++)
#pragma unroll
    for (int ni = 0; ni < 2; ni++)
#pragma unroll
      for (int kk = 0; kk < 2; kk++) {
        if constexpr (MODE == 2)
          pacc[mi][ni] = MFMA(af[mi][kk], bb[ni][kk], pacc[mi][ni]);   // D[m][n]
        else
          pacc[mi][ni] = MFMA(bb[ni][kk], af[mi][kk], pacc[mi][ni]);   // D[n][m]
      }
  __builtin_amdgcn_s_setprio(0);
}

#define PHASE_SYNC_MFMA(ACC, AF, BB)                          \
  asm volatile("s_barrier" ::: "memory");                     \
  asm volatile("s_waitcnt lgkmcnt(0)" ::: "memory");          \
  __builtin_amdgcn_sched_barrier(0);                          \
  mma16<MODE>(ACC, AF, BB);                                   \
  asm volatile("s_barrier" ::: "memory");

template <int MODE>
__device__ __forceinline__ void gemm256(const bf16* __restrict__ A,
                                        const bf16* __restrict__ Bt,
                                        int K, int m0, int n0,
                                        void* __restrict__ C0,
                                        const float* __restrict__ bias,
                                        bf16* Ls) {
  const int tid = threadIdx.x;
  const int lane = tid & 63, w = tid >> 6;   // 8 waves
  const int wm = w >> 2, wn = w & 3;         // 2M x 4N -> per-wave 128x64
  const int q = lane >> 4, c = lane & 15;
  const int swz = (c & 7) * 8;

  const int rl = tid >> 3, seg = tid & 7;
  const bf16* Ag = A + (size_t)(m0 + rl) * K + ((seg ^ (rl & 7)) * 8);
  const bf16* Bg = Bt + (size_t)(n0 + rl) * K + ((seg ^ (rl & 7)) * 8);
  const size_t K64 = (size_t)K * 64, K128 = (size_t)K * 128;
  const int ws = w * 512;

  f32x4 acc[2][2][4][2] = {};  // [h][g][mi][ni]

  // prologue: stage tile0 (order A0,A1,A2,A3,B0,B1,B2,B3) into buf0
  GLD16(Ag,              &Ls[0 + ws]);
  GLD16(Ag + K64,        &Ls[4096 + ws]);
  GLD16(Ag + K128,       &Ls[8192 + ws]);
  GLD16(Ag + K128 + K64, &Ls[12288 + ws]);
  GLD16(Bg,              &Ls[32768 + ws]);
  GLD16(Bg + K64,        &Ls[32768 + 4096 + ws]);
  GLD16(Bg + K128,       &Ls[32768 + 8192 + ws]);
  GLD16(Bg + K128 + K64, &Ls[32768 + 12288 + ws]);
  // PROLOGUE DRAIN (round-8 fix): tile-0 ds_reads at first P0 are issued before
  // P0's vmcnt, so tile 0 must be fully in LDS (all waves) before the loop.
  asm volatile("s_waitcnt vmcnt(0)" ::: "memory");
  asm volatile("s_barrier" ::: "memory");

  int cur = 0;
  for (int k0 = 0; k0 < K; k0 += 64) {
    const int nxt = cur ^ 1;
    // last tile re-stages itself (never read) to keep vmcnt arithmetic uniform
    const size_t kn = (size_t)((k0 + 64 < K) ? k0 + 64 : k0);
    const int Ab = cur * 16384, Bb = 32768 + cur * 16384;
    const int An = nxt * 16384, Bn = 32768 + nxt * 16384;

    bf16x8 af[4][2], b0[2][2], b1[2][2];

    // ---- P0: stage A0,A1(next); read Ah0+Bg0; vmcnt(2); MFMA(h0,g0) ----
    GLD16(Ag + kn,       &Ls[An + ws]);
    GLD16(Ag + kn + K64, &Ls[An + 4096 + ws]);
    ld_af(af, Ls, Ab, wm, c, q, swz);
    ld_bb(b0, Ls, Bb, wn, c, q, swz);
    asm volatile("s_waitcnt vmcnt(2)" ::: "memory");
    PHASE_SYNC_MFMA(acc[0][0], af, b0)

    // ---- P1: stage A2,A3(next); read Bg1; MFMA(h0,g1) ----
    GLD16(Ag + kn + K128,       &Ls[An + 8192 + ws]);
    GLD16(Ag + kn + K128 + K64, &Ls[An + 12288 + ws]);
    ld_bb(b1, Ls, Bb + 8192, wn, c, q, swz);
    PHASE_SYNC_MFMA(acc[0][1], af, b1)

    // ---- P2: stage B0,B1(next); read Ah1; MFMA(h1,g0) ----
    GLD16(Bg + kn,       &Ls[Bn + ws]);
    GLD16(Bg + kn + K64, &Ls[Bn + 4096 + ws]);
    ld_af(af, Ls, Ab + 8192, wm, c, q, swz);
    PHASE_SYNC_MFMA(acc[1][0], af, b0)

    // ---- P3: stage B2,B3(next); no reads; vmcnt(2); MFMA(h1,g1) ----
    GLD16(Bg + kn + K128,       &Ls[Bn + 8192 + ws]);
    GLD16(Bg + kn + K128 + K64, &Ls[Bn + 12288 + ws]);
    asm volatile("s_waitcnt vmcnt(2)" ::: "memory");
    PHASE_SYNC_MFMA(acc[1][1], af, b1)

    cur = nxt;
  }
  asm volatile("s_waitcnt vmcnt(0)" ::: "memory");  // clean exit

  if constexpr (MODE == 0 || MODE == 1) {
    // swapped: lane (q,c) of acc[h][g][mi][ni] = row m0+h*128+wm*64+mi*16+c,
    // cols n0+g*128+wn*32+ni*16+q*4 .. +3
#pragma unroll
    for (int h = 0; h < 2; h++)
#pragma unroll
      for (int g = 0; g < 2; g++)
#pragma unroll
        for (int ni = 0; ni < 2; ni++) {
          const int col = n0 + g * 128 + wn * 32 + ni * 16 + q * 4;
          float4 bv4 = {};
          if constexpr (MODE == 1) bv4 = *(const float4*)&bias[col];
#pragma unroll
          for (int mi = 0; mi < 4; mi++) {
            const int row = m0 + h * 128 + wm * 64 + mi * 16 + c;
            if constexpr (MODE == 0) {
              bf16x4 vv;
#pragma unroll
              for (int r2 = 0; r2 < 4; r2++) vv[r2] = (bf16)acc[h][g][mi][ni][r2];
              *(bf16x4*)&((bf16*)C0)[(size_t)row * 1024 + col] = vv;
            } else {
              f32x4 vv;
              vv[0] = acc[h][g][mi][ni][0] + bv4.x; vv[1] = acc[h][g][mi][ni][1] + bv4.y;
              vv[2] = acc[h][g][mi][ni][2] + bv4.z; vv[3] = acc[h][g][mi][ni][3] + bv4.w;
              *(f32x4*)&((float*)C0)[(size_t)row * 1024 + col] = vv;
            }
          }
        }
  } else {
    // normal: lane (q,c) holds rows rbase+q*4..+3 (keys), col fixed; sigma scatter.
#pragma unroll
    for (int h = 0; h < 2; h++)
#pragma unroll
      for (int g = 0; g < 2; g++)
#pragma unroll
        for (int ni = 0; ni < 2; ni++) {
          const int col = n0 + g * 128 + wn * 32 + ni * 16 + c;
#pragma unroll
          for (int mi = 0; mi < 4; mi++) {
            const int rbase = m0 + h * 128 + wm * 64 + mi * 16 + q * 4;
            const int b = rbase >> 10, key = rbase & 1023;
            bf16* VT = (bf16*)C0;
            const int hh = col >> 6, d = col & 63;
            const int kl = key & 63;
            const int pkey = (key & ~63) | (kl & 32) | ((kl & 12) << 1) | ((kl & 16) >> 2);
            bf16x4 vv;
#pragma unroll
            for (int r2 = 0; r2 < 4; r2++) vv[r2] = (bf16)acc[h][g][mi][ni][r2];
            *(bf16x4*)&VT[((size_t)(b * 16 + hh) * 64 + d) * 1024 + pkey] = vv;
          }
        }
  }
}

// ---------------- fused Q+K+V projections, 256 blocks x 512 threads ----------------
__global__ __launch_bounds__(512) void proj_k(const bf16* __restrict__ xb,
                                              const bf16* __restrict__ ctxb,
                                              const bf16* __restrict__ WqT,
                                              const bf16* __restrict__ WkvT,
                                              bf16* __restrict__ Q,
                                              bf16* __restrict__ Kp,
                                              bf16* __restrict__ VT) {
  extern __shared__ __align__(16) bf16 Ls[];
  const int bid = blockIdx.x;
  if (bid < 128) {        // Q: M=8192 (32 rt), N=1024 (4 ct), K=1024
    const int x = bid & 7, i = bid >> 3;         // i 0..15
    const int rt = x * 4 + (i >> 2), ct = i & 3;
    gemm256<0>(xb, WqT, 1024, rt * 256, ct * 256, Q, nullptr, Ls);
  } else if (bid < 192) { // K: M=4096 (16 rt), N=1024, K=768
    const int t = bid - 128, x = t & 7, i = t >> 3;  // i 0..7
    const int rt = x * 2 + (i >> 2), ct = i & 3;
    gemm256<0>(ctxb, WkvT, 768, rt * 256, ct * 256, Kp, nullptr, Ls);
  } else {                // V: M=4096, N=1024, K=768 -> sigma V^T
    const int t = bid - 192, x = t & 7, i = t >> 3;
    const int rt = x * 2 + (i >> 2), ct = i & 3;
    gemm256<2>(ctxb, WkvT + (size_t)1024 * 768, 768, rt * 256, ct * 256, VT, nullptr, Ls);
  }
}

// ---------------- output projection (round-3/4 known-good 128x128 body) ----------------
__device__ __forceinline__ void gemm_body_out(const bf16* __restrict__ A,
                                              const bf16* __restrict__ Bt,
                                              int K, int m0, int n0,
                                              float* __restrict__ C0,
                                              const float* __restrict__ bias,
                                              bf16* As, bf16* Bs) {
  const int tid = threadIdx.x;
  const int lane = tid & 63, wave = tid >> 6;
  const int wm = wave >> 1, wn = wave & 1;
  const int q = lane >> 4, c = lane & 15;

  f32x4 acc[4][4] = {};
  const int r = tid >> 3;
  const int col8 = ((tid & 7) * 8) ^ ((r & 7) * 8);
  const bf16* Ag = A + (size_t)(m0 + r) * K + col8;
  const bf16* Bg = Bt + (size_t)(n0 + r) * K + col8;
  const size_t K32 = (size_t)K * 32;
  bf16* AsW = As + wave * 512;
  bf16* BsW = Bs + wave * 512;
  const int swz = (c & 7) * 8;

  for (int k0 = 0; k0 < K; k0 += 64) {
    __syncthreads();
    GLD16(Ag + k0,            AsW);
    GLD16(Ag + k0 + K32,      AsW + 2048);
    GLD16(Ag + k0 + 2 * K32,  AsW + 4096);
    GLD16(Ag + k0 + 3 * K32,  AsW + 6144);
    GLD16(Bg + k0,            BsW);
    GLD16(Bg + k0 + K32,      BsW + 2048);
    GLD16(Bg + k0 + 2 * K32,  BsW + 4096);
    GLD16(Bg + k0 + 3 * K32,  BsW + 6144);
    __syncthreads();
#pragma unroll
    for (int kk = 0; kk < 2; kk++) {
      const int cx = (kk * 32 + q * 8) ^ swz;
      bf16x8 af[4], bfr[4];
#pragma unroll
      for (int mi = 0; mi < 4; mi++)
        af[mi] = *(const bf16x8*)&As[(wm * 64 + mi * 16 + c) * 64 + cx];
#pragma unroll
      for (int ni = 0; ni < 4; ni++)
        bfr[ni] = *(const bf16x8*)&Bs[(wn * 64 + ni * 16 + c) * 64 + cx];
      __builtin_amdgcn_s_setprio(1);
#pragma unroll
      for (int mi = 0; mi < 4; mi++)
#pragma unroll
        for (int ni = 0; ni < 4; ni++)
          acc[mi][ni] = MFMA(bfr[ni], af[mi], acc[mi][ni]);   // D[n][m]
      __builtin_amdgcn_s_setprio(0);
    }
  }

#pragma unroll
  for (int ni = 0; ni < 4; ni++) {
    const int col = n0 + wn * 64 + ni * 16 + q * 4;
    float4 bv4 = *(const float4*)&bias[col];
#pragma unroll
    for (int mi = 0; mi < 4; mi++) {
      const int row = m0 + wm * 64 + mi * 16 + c;
      f32x4 vv;
      vv[0] = acc[mi][ni][0] + bv4.x; vv[1] = acc[mi][ni][1] + bv4.y;
      vv[2] = acc[mi][ni][2] + bv4.z; vv[3] = acc[mi][ni][3] + bv4.w;
      *(f32x4*)&C0[(size_t)row * 1024 + col] = vv;
    }
  }
}

__global__ __launch_bounds__(256) void out_k(const bf16* __restrict__ O,
                                             const bf16* __restrict__ WoT,
                                             float* __restrict__ out,
                                             const float* __restrict__ bo) {
  __shared__ __align__(16) bf16 As[8192];
  __shared__ __align__(16) bf16 Bs[8192];
  const int bid = blockIdx.x;
  const int s = (bid & 7) * 64 + (bid >> 3);   // XCD chunk-swizzle
  gemm_body_out(O, WoT, 1024, (s >> 3) * 128, (s & 7) * 128, out, bo, As, Bs);
}

// ---------------- flash attention (round-6 verified, 41.6us): dbuf, swizzled [64][64] ----------------
// 512 blocks, 4 waves, 64 q-rows/wave. One barrier/tile, write-late staging.
__global__ __launch_bounds__(256, 2) void attn_k(const bf16* __restrict__ Qg,
                                                 const bf16* __restrict__ Kg,
                                                 const bf16* __restrict__ VTg,
                                                 bf16* __restrict__ Og) {
  __shared__ __align__(16) bf16 Ks[2][64][64];
  __shared__ __align__(16) bf16 Vt[2][64][64];
  const int tid = threadIdx.x;
  const int lane = tid & 63, w = tid >> 6;
  const int q = lane >> 4, c = lane & 15;
  const int bid = blockIdx.x;                  // 512 flat
  const int pair = (bid & 7) * 8 + (bid >> 6); // 0..63 ; 8 pairs per XCD
  const int head = pair & 15, b = pair >> 4;
  const int q0 = ((bid >> 3) & 7) * 256;

  bf16x8 aQ[4][2];
#pragma unroll
  for (int mj = 0; mj < 4; mj++)
#pragma unroll
    for (int ks = 0; ks < 2; ks++)
      aQ[mj][ks] = *(const bf16x8*)(Qg + (size_t)(b * 2048 + q0 + w * 64 + mj * 16 + c) * 1024 +
                                    head * 64 + ks * 32 + q * 8);

  f32x4 o[4][4] = {};
  f32x4 ol[4] = {};  // l via ones-MFMA: lane (q,c) reg r = l[qrow mi*16+q*4+r]
  bf16x8 vone;
#pragma unroll
  for (int i = 0; i < 8; i++) vone[i] = (bf16)1.0f;

  const int srow = tid >> 2, sc = tid & 3;
  const int ws0 = ((2 * sc) ^ (srow & 7)) * 8;      // swizzled write slots
  const int ws1 = ((2 * sc + 1) ^ (srow & 7)) * 8;
  const int rsw = c & 7;                            // read-side slot XOR
  const bf16* Kbase = Kg + (size_t)(b * 1024 + srow) * 1024 + head * 64 + sc * 16;
  const bf16* Vbase = VTg + ((size_t)(b * 16 + head) * 64 + srow) * 1024 + sc * 16;

  // prologue: tile 0 -> regs -> buf0
  bf16x8 rk0 = *(const bf16x8*)(Kbase);
  bf16x8 rk1 = *(const bf16x8*)(Kbase + 8);
  bf16x8 rv0 = *(const bf16x8*)(Vbase);
  bf16x8 rv1 = *(const bf16x8*)(Vbase + 8);
  *(bf16x8*)&Ks[0][srow][ws0] = rk0;
  *(bf16x8*)&Ks[0][srow][ws1] = rk1;
  *(bf16x8*)&Vt[0][srow][ws0] = rv0;
  *(bf16x8*)&Vt[0][srow][ws1] = rv1;
  __syncthreads();

  for (int kt = 0; kt < 16; kt++) {
    const int cur = kt & 1, nxt = cur ^ 1;
    if (kt < 15) {  // issue next tile's loads; consumed by the write phase at iter end
      const size_t ko = (size_t)(kt + 1) * 65536;
      const int vo = (kt + 1) * 64;
      rk0 = *(const bf16x8*)(Kbase + ko);
      rk1 = *(const bf16x8*)(Kbase + ko + 8);
      rv0 = *(const bf16x8*)(Vbase + vo);
      rv1 = *(const bf16x8*)(Vbase + vo + 8);
    }

    // S^T = K @ Q^T : lane (q,c) reg r of st[mj][ni] = S[qrow=mj*16+c][key=ni*16+q*4+r]
    f32x4 st[4][4] = {};
#pragma unroll
    for (int ks = 0; ks < 2; ks++) {
      bf16x8 ak[4];
#pragma unroll
      for (int ni = 0; ni < 4; ni++)
        ak[ni] = *(const bf16x8*)&Ks[cur][ni * 16 + c][((ks * 4 + q) ^ rsw) * 8];
      __builtin_amdgcn_s_setprio(1);
#pragma unroll
      for (int mj = 0; mj < 4; mj++)
#pragma unroll
        for (int ni = 0; ni < 4; ni++)
          st[mj][ni] = MFMA(ak[ni], aQ[mj][ks], st[mj][ni]);
      __builtin_amdgcn_s_setprio(0);
    }

    // p = exp2(s) (scale pre-folded into Wq); pack straight to bf16
    int pk[4][4][2];
#pragma unroll
    for (int mj = 0; mj < 4; mj++)
#pragma unroll
      for (int ni = 0; ni < 4; ni++) {
        float p0 = __builtin_amdgcn_exp2f(st[mj][ni][0]);
        float p1 = __builtin_amdgcn_exp2f(st[mj][ni][1]);
        float p2 = __builtin_amdgcn_exp2f(st[mj][ni][2]);
        float p3 = __builtin_amdgcn_exp2f(st[mj][ni][3]);
        HI h0, h1;
        h0.h[0] = (bf16)p0; h0.h[1] = (bf16)p1;
        h1.h[0] = (bf16)p2; h1.h[1] = (bf16)p3;
        pk[mj][ni][0] = h0.i;
        pk[mj][ni][1] = h1.i;
      }

    // O += P @ V in kappa key-order; sigma-permuted Vt makes B-frag one b128.
    // l += P @ 1 rides on the same A-fragment (permutation-invariant).
#pragma unroll
    for (int ks2 = 0; ks2 < 2; ks2++) {
      bf16x8 bv[4];
#pragma unroll
      for (int ni = 0; ni < 4; ni++)
        bv[ni] = *(const bf16x8*)&Vt[cur][ni * 16 + c][((ks2 * 4 + q) ^ rsw) * 8];
#pragma unroll
      for (int mi = 0; mi < 4; mi++) {
        I4B8 pa;
        pa.i.x = pk[mi][2 * ks2][0];
        pa.i.y = pk[mi][2 * ks2][1];
        pa.i.z = pk[mi][2 * ks2 + 1][0];
        pa.i.w = pk[mi][2 * ks2 + 1][1];
        __builtin_amdgcn_s_setprio(1);
#pragma unroll
        for (int ni = 0; ni < 4; ni++)
          o[mi][ni] = MFMA(pa.v, bv[ni], o[mi][ni]);
        ol[mi] = MFMA(pa.v, vone, ol[mi]);
        __builtin_amdgcn_s_setprio(0);
      }
    }

    if (kt < 15) {  // write-late: regs (tile kt+1) -> buf[nxt]
      *(bf16x8*)&Ks[nxt][srow][ws0] = rk0;
      *(bf16x8*)&Ks[nxt][srow][ws1] = rk1;
      *(bf16x8*)&Vt[nxt][srow][ws0] = rv0;
      *(bf16x8*)&Vt[nxt][srow][ws1] = rv1;
    }
    __syncthreads();
  }

  // epilogue: ol[mi][r] is already l for qrow mi*16+q*4+r (every c holds a copy)
#pragma unroll
  for (int mi = 0; mi < 4; mi++) {
    float inv[4];
#pragma unroll
    for (int r = 0; r < 4; r++) inv[r] = 1.0f / ol[mi][r];
#pragma unroll
    for (int ni = 0; ni < 4; ni++)
#pragma unroll
      for (int r = 0; r < 4; r++) {
        const int qrow = q0 + w * 64 + mi * 16 + q * 4 + r;
        const int col = head * 64 + ni * 16 + c;
        Og[(size_t)(b * 2048 + qrow) * 1024 + col] = (bf16)(o[mi][ni][r] * inv[r]);
      }
  }
}

extern "C" void kernel_launch(void* const* d_in, const int* in_sizes, int n_in,
                              void* d_out, int out_size, void* d_ws, size_t ws_size,
                              hipStream_t stream) {
  (void)in_sizes; (void)n_in; (void)out_size; (void)ws_size;
  const float* x   = (const float*)d_in[0];
  const float* ctx = (const float*)d_in[1];
  const float* Wq  = (const float*)d_in[2];
  const float* Wk  = (const float*)d_in[3];
  const float* Wv  = (const float*)d_in[4];
  const float* Wo  = (const float*)d_in[5];
  const float* bo  = (const float*)d_in[6];
  float* out = (float*)d_out;

  char* ws = (char*)d_ws;
  const size_t MB = 1u << 20;
  bf16* WqT  = (bf16*)(ws);                 // 2 MiB   [1024][1024] (x 0.18033688)
  bf16* WkvT = (bf16*)(ws + 2 * MB);        // 3 MiB   [2048][768]
  bf16* WoT  = (bf16*)(ws + 5 * MB);        // 2 MiB
  bf16* ctxb = (bf16*)(ws + 7 * MB);        // 6 MiB   [4096][768]
  bf16* xb   = (bf16*)(ws + 13 * MB);       // 16 MiB  [8192][1024]; reused as O after Q-proj
  bf16* Q    = (bf16*)(ws + 29 * MB);       // 16 MiB
  bf16* Kp   = (bf16*)(ws + 45 * MB);       // 8 MiB
  bf16* VT   = (bf16*)(ws + 53 * MB);       // 8 MiB   [4][16][64][1024] sigma-permuted keys
  bf16* O    = xb;

  prep_k<<<5632 + 4096, 256, 0, stream>>>(x, xb, ctx, ctxb, Wq, WqT, Wk, WkvT, Wv, Wo, WoT);

  proj_k<<<256, 512, 131072, stream>>>(xb, ctxb, WqT, WkvT, Q, Kp, VT);

  attn_k<<<512, 256, 0, stream>>>(Q, Kp, VT, O);

  out_k<<<512, 256, 0, stream>>>(O, WoT, out, bo);
}